// Round 1
// 511.961 us; speedup vs baseline: 1.0001x; 1.0001x over previous
//
#include <hip/hip_runtime.h>

#define S_LEN  4096
#define DMODEL 2048
#define NHEADS 16
#define HDIM   128

typedef __bf16 bf16x8 __attribute__((ext_vector_type(8)));
typedef __bf16 bf16x2 __attribute__((ext_vector_type(2)));
typedef float  f32x4  __attribute__((ext_vector_type(4)));

__device__ __forceinline__ unsigned short f2b(float f) {
    unsigned int u = __float_as_uint(f);
    unsigned int r = (u + 0x7fffu + ((u >> 16) & 1u)) >> 16;
    return (unsigned short)r;
}

// pack two fp32 -> one dword of bf16 (lo = a, hi = b)
__device__ __forceinline__ unsigned int pkbf16(float a, float b) {
#if __has_builtin(__builtin_amdgcn_cvt_pk_bf16_f32)
    bf16x2 t = __builtin_amdgcn_cvt_pk_bf16_f32(a, b);
    return *(unsigned int*)&t;
#else
    return (unsigned int)f2b(a) | ((unsigned int)f2b(b) << 16);
#endif
}

__device__ __forceinline__ f32x4 mfma16(bf16x8 a, bf16x8 b, f32x4 c) {
    return __builtin_amdgcn_mfma_f32_16x16x32_bf16(a, b, c, 0, 0, 0);
}

// async global->LDS, 16B per lane; LDS dest = wave-uniform base + lane*16
__device__ __forceinline__ void ldg2lds16(const void* g, void* l) {
    __builtin_amdgcn_global_load_lds(
        (__attribute__((address_space(1))) void*)(void*)g,
        (__attribute__((address_space(3))) void*)l, 16, 0, 0);
}

// ---------------------------------------------------------------------------
// fp32 -> bf16 converts
// ---------------------------------------------------------------------------
__global__ __launch_bounds__(256) void cvt_bf16(
    const float* __restrict__ src, unsigned short* __restrict__ dst, int n4)
{
    int i = blockIdx.x * blockDim.x + threadIdx.x;
    if (i < n4) {
        float4 v = ((const float4*)src)[i];
        uint2 h;
        h.x = pkbf16(v.x, v.y); h.y = pkbf16(v.z, v.w);
        ((uint2*)dst)[i] = h;
    }
}

__global__ __launch_bounds__(256) void cvt_bf16_w4(
    const float* __restrict__ w0, const float* __restrict__ w1,
    const float* __restrict__ w2, const float* __restrict__ w3,
    unsigned short* __restrict__ d0, unsigned short* __restrict__ d1,
    unsigned short* __restrict__ d2, unsigned short* __restrict__ d3)
{
    const int z = blockIdx.y;
    const float* src = (z == 0) ? w0 : (z == 1) ? w1 : (z == 2) ? w2 : w3;
    unsigned short* dst = (z == 0) ? d0 : (z == 1) ? d1 : (z == 2) ? d2 : d3;
    int i = blockIdx.x * blockDim.x + threadIdx.x;
    float4 v = ((const float4*)src)[i];
    uint2 h;
    h.x = pkbf16(v.x, v.y); h.y = pkbf16(v.z, v.w);
    ((uint2*)dst)[i] = h;
}

// ---------------------------------------------------------------------------
// m97-structure bf16 GEMM (QKV variant)
// ---------------------------------------------------------------------------
__global__ __launch_bounds__(256, 2) void gemm_qkv(
    const unsigned short* __restrict__ xb,
    const unsigned short* __restrict__ Wqb, const float* __restrict__ bq,
    const unsigned short* __restrict__ Wkb, const float* __restrict__ bk,
    const unsigned short* __restrict__ Wvb, const float* __restrict__ bv,
    unsigned short* __restrict__ Qb, unsigned short* __restrict__ Kb,
    unsigned short* __restrict__ Vb)
{
    const int z = blockIdx.z;
    const unsigned short* B = (z == 0) ? Wqb : (z == 1) ? Wkb : Wvb;
    const float* bias        = (z == 0) ? bq  : (z == 1) ? bk  : bv;
    unsigned short* C        = (z == 0) ? Qb  : (z == 1) ? Kb  : Vb;
    const float oscale = (z == 0) ? 0.12751743f : 1.0f;  // log2(e)/sqrt(128)

    __shared__ alignas(16) unsigned short As[128 * 32];
    __shared__ alignas(16) unsigned short Bs[128 * 32];

    const int tid = threadIdx.x;
    const int m0 = blockIdx.y * 128, n0 = blockIdx.x * 128;
    const int w = tid >> 6, lane = tid & 63, lo = lane & 15, qd = lane >> 4;
    const int wm = (w >> 1) * 64, wn = (w & 1) * 64;
    const int rsel = lane >> 2, csel = (lane & 3) * 8;

    f32x4 acc[4][4] = {};

    for (int k0 = 0; k0 < DMODEL; k0 += 32) {
#pragma unroll
        for (int i = 0; i < 2; i++) {
            int c = w * 2 + i;
            ldg2lds16(&xb[(size_t)(m0 + c * 16 + rsel) * DMODEL + k0 + csel],
                      &As[c * 512]);
            ldg2lds16(&B [(size_t)(n0 + c * 16 + rsel) * DMODEL + k0 + csel],
                      &Bs[c * 512]);
        }
        __syncthreads();

        bf16x8 af[4], bfr[4];
#pragma unroll
        for (int i = 0; i < 4; i++)
            af[i] = *(const bf16x8*)&As[(wm + i * 16 + lo) * 32 + qd * 8];
#pragma unroll
        for (int j = 0; j < 4; j++)
            bfr[j] = *(const bf16x8*)&Bs[(wn + j * 16 + lo) * 32 + qd * 8];
#pragma unroll
        for (int i = 0; i < 4; i++)
#pragma unroll
            for (int j = 0; j < 4; j++)
                acc[i][j] = mfma16(af[i], bfr[j], acc[i][j]);
        __syncthreads();
    }

#pragma unroll
    for (int j = 0; j < 4; j++) {
        int n = n0 + wn + j * 16 + lo;
        float bv_ = bias[n];
#pragma unroll
        for (int i = 0; i < 4; i++) {
#pragma unroll
            for (int r = 0; r < 4; r++) {
                int m = m0 + wm + i * 16 + qd * 4 + r;
                C[(size_t)m * DMODEL + n] = f2b((acc[i][j][r] + bv_) * oscale);
            }
        }
    }
}

// Output projection variant: fp32 out + bias.
__global__ __launch_bounds__(256, 2) void gemm_out(
    const unsigned short* __restrict__ Aatt, const unsigned short* __restrict__ Wob,
    const float* __restrict__ bo, float* __restrict__ out)
{
    __shared__ alignas(16) unsigned short As[128 * 32];
    __shared__ alignas(16) unsigned short Bs[128 * 32];

    const int tid = threadIdx.x;
    const int m0 = blockIdx.y * 128, n0 = blockIdx.x * 128;
    const int w = tid >> 6, lane = tid & 63, lo = lane & 15, qd = lane >> 4;
    const int wm = (w >> 1) * 64, wn = (w & 1) * 64;
    const int rsel = lane >> 2, csel = (lane & 3) * 8;

    f32x4 acc[4][4] = {};

    for (int k0 = 0; k0 < DMODEL; k0 += 32) {
#pragma unroll
        for (int i = 0; i < 2; i++) {
            int c = w * 2 + i;
            ldg2lds16(&Aatt[(size_t)(m0 + c * 16 + rsel) * DMODEL + k0 + csel],
                      &As[c * 512]);
            ldg2lds16(&Wob [(size_t)(n0 + c * 16 + rsel) * DMODEL + k0 + csel],
                      &Bs[c * 512]);
        }
        __syncthreads();

        bf16x8 af[4], bfr[4];
#pragma unroll
        for (int i = 0; i < 4; i++)
            af[i] = *(const bf16x8*)&As[(wm + i * 16 + lo) * 32 + qd * 8];
#pragma unroll
        for (int j = 0; j < 4; j++)
            bfr[j] = *(const bf16x8*)&Bs[(wn + j * 16 + lo) * 32 + qd * 8];
#pragma unroll
        for (int i = 0; i < 4; i++)
#pragma unroll
            for (int j = 0; j < 4; j++)
                acc[i][j] = mfma16(af[i], bfr[j], acc[i][j]);
        __syncthreads();
    }

#pragma unroll
    for (int j = 0; j < 4; j++) {
        int n = n0 + wn + j * 16 + lo;
        float bv_ = bo[n];
#pragma unroll
        for (int i = 0; i < 4; i++) {
#pragma unroll
            for (int r = 0; r < 4; r++) {
                int m = m0 + wm + i * 16 + qd * 4 + r;
                out[(size_t)m * DMODEL + n] = acc[i][j][r] + bv_;
            }
        }
    }
}

// ---------------------------------------------------------------------------
// V transpose: Vb [s][n] -> Vt [n][s]
// ---------------------------------------------------------------------------
__global__ __launch_bounds__(256) void transpose_v(
    const unsigned short* __restrict__ Vb, unsigned short* __restrict__ Vt)
{
    __shared__ unsigned short tile[64 * 67];
    const int s0 = blockIdx.x * 64;
    const int d0 = blockIdx.y * 64;
    const int tid = threadIdx.x;
#pragma unroll
    for (int i = 0; i < 2; i++) {
        int chunk = tid + i * 256;
        int r = chunk >> 3, c8 = (chunk & 7) * 8;
        uint4 v = *(const uint4*)&Vb[(size_t)(s0 + r) * DMODEL + d0 + c8];
        const unsigned short* p = (const unsigned short*)&v;
#pragma unroll
        for (int j = 0; j < 8; j++) tile[r * 67 + c8 + j] = p[j];
    }
    __syncthreads();
#pragma unroll
    for (int i = 0; i < 2; i++) {
        int chunk = tid + i * 256;
        int r = chunk >> 3, c8 = (chunk & 7) * 8;
        unsigned short tmp[8];
#pragma unroll
        for (int j = 0; j < 8; j++) tmp[j] = tile[(c8 + j) * 67 + r];
        *(uint4*)&Vt[(size_t)(d0 + r) * S_LEN + s0 + c8] = *(uint4*)tmp;
    }
}

// ---------------------------------------------------------------------------
// Flash attention v6: S^T orientation + double-buffered K/V prefetch.
//   v5 structure was stage -> sync(vmcnt drain) -> compute -> sync: every
//   wave ate the full L2 latency serially per 64-key tile. v6 prefetches
//   tile t+1 into buf^1 at the top of iteration t, computes on buf, then a
//   SINGLE __syncthreads per tile (its implicit vmcnt(0) lands after a full
//   iteration of compute). LDS 48->80 KB: still exactly 2 blocks/CU, which
//   is what the 512-block grid gives anyway -> zero occupancy cost.
//   s_setprio(1) around the MFMA clusters (T5): the 2 resident blocks drift
//   to different phases, so priority arbitration favors the MFMA-phase block.
// ---------------------------------------------------------------------------
__global__ __launch_bounds__(256, 2) void attn_kernel(
    const unsigned short* __restrict__ Qb, const unsigned short* __restrict__ Kb,
    const unsigned short* __restrict__ Vt, unsigned short* __restrict__ Ob)
{
    const int id = blockIdx.x;
    const int xcd = id & 7, slot = id >> 3;
    const int h  = (xcd << 1) | (slot >> 5);
    const int q0 = (slot & 31) * 128;

    __shared__ alignas(16) unsigned short Ks[2][64 * 128];    // [buf][key][d] swizzled
    __shared__ alignas(16) unsigned short Vts[2][128 * 64];   // [buf][d][key] swizzled
    __shared__ alignas(16) unsigned short Ps[4][32 * 64];     // per-wave [q][key] swizzled

    const int tid = threadIdx.x;
    const int w = tid >> 6, lane = tid & 63, lo = lane & 15, qd = lane >> 4;

    // Q fragments direct from global: wave w owns q rows w*32 .. w*32+31
    bf16x8 qf[2][4];
#pragma unroll
    for (int mt = 0; mt < 2; mt++) {
        const unsigned short* qrow =
            &Qb[(size_t)(q0 + w * 32 + mt * 16 + lo) * DMODEL + h * HDIM];
#pragma unroll
        for (int kk = 0; kk < 4; kk++)
            qf[mt][kk] = *(const bf16x8*)&qrow[kk * 32 + qd * 8];
    }

    f32x4 o_acc[2][8] = {};
    float l_run[2] = {0.f, 0.f};   // lane's q = mt*16+lo

    // --- staging (async, 16B/lane). K: wave w -> key rows w*16..w*16+15;
    //     V: wave w -> d rows w*32..w*32+31. Same swizzles as v5.
#define STAGE_KV(key0_, KsB_, VtsB_)                                          \
    {                                                                         \
        _Pragma("unroll")                                                     \
        for (int i = 0; i < 4; i++) {                                         \
            int r = w * 16 + i * 4 + (lane >> 4);                             \
            int c = (lane & 15) ^ (r & 7);                                    \
            ldg2lds16(&Kb[(size_t)((key0_) + r) * DMODEL + h * HDIM + c * 8], \
                      &(KsB_)[(w * 16 + i * 4) * 128]);                       \
        }                                                                     \
        _Pragma("unroll")                                                     \
        for (int i = 0; i < 4; i++) {                                         \
            int r = w * 32 + i * 8 + (lane >> 3);                             \
            int c = (lane & 7) ^ (r & 7);                                     \
            ldg2lds16(&Vt[(size_t)(h * HDIM + r) * S_LEN + (key0_) + c * 8],  \
                      &(VtsB_)[(w * 32 + i * 8) * 64]);                       \
        }                                                                     \
    }

    // prologue: stage tile 0 into buf 0
    STAGE_KV(0, Ks[0], Vts[0]);
    __syncthreads();

    int cur = 0;
    for (int kb = 0; kb < S_LEN / 64; kb++) {
        // prefetch tile kb+1 into the alternate buffers; completes under
        // this iteration's compute, drained by the end-of-iter barrier.
        if (kb + 1 < S_LEN / 64)
            STAGE_KV((kb + 1) * 64, Ks[cur ^ 1], Vts[cur ^ 1]);

        const unsigned short* KsC  = Ks[cur];
        const unsigned short* VtsC = Vts[cur];

        // S^T[key 64][q 32] = K Q^T : A = K-frag (m=key), B = Q-frag (n=q)
        f32x4 s[4][2] = {};
        __builtin_amdgcn_s_setprio(1);
#pragma unroll
        for (int kk = 0; kk < 4; kk++) {
#pragma unroll
            for (int t = 0; t < 4; t++) {
                bf16x8 kf = *(const bf16x8*)
                    &KsC[(t * 16 + lo) * 128 + (((kk * 4 + qd) ^ (lo & 7)) * 8)];
                s[t][0] = mfma16(kf, qf[0][kk], s[t][0]);
                s[t][1] = mfma16(kf, qf[1][kk], s[t][1]);
            }
        }
        __builtin_amdgcn_s_setprio(0);

        // exp2 + packed P write + per-lane l accumulate.
        // Lane's C-tile: q = mt*16+lo, keys = t*16 + qd*4 + r (r consecutive!)
#pragma unroll
        for (int mt = 0; mt < 2; mt++) {
            const int row = mt * 16 + lo;
            float lsum = 0.f;
#pragma unroll
            for (int t = 0; t < 4; t++) {
                float p0 = exp2f(s[t][mt][0]);
                float p1 = exp2f(s[t][mt][1]);
                float p2 = exp2f(s[t][mt][2]);
                float p3 = exp2f(s[t][mt][3]);
                lsum += (p0 + p1) + (p2 + p3);
                uint2 pkv;
                pkv.x = pkbf16(p0, p1);
                pkv.y = pkbf16(p2, p3);
                // 16B chunk c16 = t*2+(qd>>1), swizzled by (row&7); 8B half = qd&1
                int swz = (t * 2 + (qd >> 1)) ^ (lo & 7);
                *(uint2*)&Ps[w][row * 64 + swz * 8 + (qd & 1) * 4] = pkv;
            }
            l_run[mt] += lsum;
        }
        asm volatile("s_waitcnt lgkmcnt(0)" ::: "memory");  // wave-local P w->r

        // O += P V
        __builtin_amdgcn_s_setprio(1);
#pragma unroll
        for (int kk = 0; kk < 2; kk++) {
            bf16x8 pf[2];
#pragma unroll
            for (int mt = 0; mt < 2; mt++)
                pf[mt] = *(const bf16x8*)
                    &Ps[w][(mt * 16 + lo) * 64 + (((kk * 4 + qd) ^ (lo & 7)) * 8)];
#pragma unroll
            for (int dt = 0; dt < 8; dt++) {
                bf16x8 vf = *(const bf16x8*)
                    &VtsC[(dt * 16 + lo) * 64 + (((kk * 4 + qd) ^ (lo & 7)) * 8)];
                o_acc[0][dt] = mfma16(pf[0], vf, o_acc[0][dt]);
                o_acc[1][dt] = mfma16(pf[1], vf, o_acc[1][dt]);
            }
        }
        __builtin_amdgcn_s_setprio(0);

        // single barrier per tile: drains the prefetch (vmcnt) AND protects
        // the buffer we overwrite next iteration.
        __syncthreads();
        cur ^= 1;
    }
#undef STAGE_KV

    // epilogue: l lives at lane (q & 15) after qd-reduction; redistribute to
    // the O C-layout rows (q = mt*16 + qd*4 + r) via bpermute shuffle.
#pragma unroll
    for (int mt = 0; mt < 2; mt++) {
        float l = l_run[mt];
        l += __shfl_xor(l, 16);
        l += __shfl_xor(l, 32);          // now uniform across qd for q=mt*16+lo
        float inv_l[4];
#pragma unroll
        for (int r = 0; r < 4; r++)
            inv_l[r] = 1.0f / __shfl(l, qd * 4 + r);
#pragma unroll
        for (int dt = 0; dt < 8; dt++) {
#pragma unroll
            for (int r = 0; r < 4; r++) {
                int row = q0 + w * 32 + mt * 16 + qd * 4 + r;
                int col = h * HDIM + dt * 16 + lo;
                Ob[(size_t)row * DMODEL + col] = f2b(o_acc[mt][dt][r] * inv_l[r]);
            }
        }
    }
}

// ---------------------------------------------------------------------------
extern "C" void kernel_launch(void* const* d_in, const int* in_sizes, int n_in,
                              void* d_out, int out_size, void* d_ws, size_t ws_size,
                              hipStream_t stream)
{
    const float* x  = (const float*)d_in[0];
    const float* Wq = (const float*)d_in[1];
    const float* bq = (const float*)d_in[2];
    const float* Wk = (const float*)d_in[3];
    const float* bk = (const float*)d_in[4];
    const float* Wv = (const float*)d_in[5];
    const float* bv = (const float*)d_in[6];
    const float* Wo = (const float*)d_in[7];
    const float* bo = (const float*)d_in[8];
    float* out = (float*)d_out;

    const size_t N = (size_t)S_LEN * DMODEL;   // 8M elems
    const size_t W = (size_t)DMODEL * DMODEL;  // 4M elems
    unsigned short* Qb  = (unsigned short*)d_ws;
    unsigned short* Kb  = Qb + N;
    unsigned short* Vb  = Kb + N;
    unsigned short* xbv = Vb + N;
    unsigned short* Wqb = xbv + N;
    unsigned short* Wkb = Wqb + W;
    unsigned short* Wvb = Wkb + W;
    unsigned short* Wob = Wvb + W;
    unsigned short* Vt  = xbv;   // alias after gemm_qkv
    unsigned short* Ob  = Vb;    // alias after transpose

    cvt_bf16<<<(int)(N / 4 / 256), 256, 0, stream>>>(x, xbv, (int)(N / 4));
    cvt_bf16_w4<<<dim3((unsigned)(W / 4 / 256), 4), 256, 0, stream>>>(
        Wq, Wk, Wv, Wo, Wqb, Wkb, Wvb, Wob);

    gemm_qkv<<<dim3(DMODEL / 128, S_LEN / 128, 3), 256, 0, stream>>>(
        xbv, Wqb, bq, Wkb, bk, Wvb, bv, Qb, Kb, Vb);

    transpose_v<<<dim3(S_LEN / 64, DMODEL / 64), 256, 0, stream>>>(Vb, Vt);

    attn_kernel<<<512, 256, 0, stream>>>(Qb, Kb, Vt, Ob);

    gemm_out<<<dim3(DMODEL / 128, S_LEN / 128), 256, 0, stream>>>(Ob, Wob, bo, out);
}

// Round 2
// 507.165 us; speedup vs baseline: 1.0095x; 1.0095x over previous
//
#include <hip/hip_runtime.h>

#define S_LEN  4096
#define DMODEL 2048
#define NHEADS 16
#define HDIM   128

typedef __bf16 bf16x8 __attribute__((ext_vector_type(8)));
typedef __bf16 bf16x2 __attribute__((ext_vector_type(2)));
typedef float  f32x4  __attribute__((ext_vector_type(4)));

__device__ __forceinline__ unsigned short f2b(float f) {
    unsigned int u = __float_as_uint(f);
    unsigned int r = (u + 0x7fffu + ((u >> 16) & 1u)) >> 16;
    return (unsigned short)r;
}

// pack two fp32 -> one dword of bf16 (lo = a, hi = b)
__device__ __forceinline__ unsigned int pkbf16(float a, float b) {
#if __has_builtin(__builtin_amdgcn_cvt_pk_bf16_f32)
    bf16x2 t = __builtin_amdgcn_cvt_pk_bf16_f32(a, b);
    return *(unsigned int*)&t;
#else
    return (unsigned int)f2b(a) | ((unsigned int)f2b(b) << 16);
#endif
}

__device__ __forceinline__ f32x4 mfma16(bf16x8 a, bf16x8 b, f32x4 c) {
    return __builtin_amdgcn_mfma_f32_16x16x32_bf16(a, b, c, 0, 0, 0);
}

// async global->LDS, 16B per lane; LDS dest = wave-uniform base + lane*16
__device__ __forceinline__ void ldg2lds16(const void* g, void* l) {
    __builtin_amdgcn_global_load_lds(
        (__attribute__((address_space(1))) void*)(void*)g,
        (__attribute__((address_space(3))) void*)l, 16, 0, 0);
}

// ---------------------------------------------------------------------------
// fp32 -> bf16 converts
// ---------------------------------------------------------------------------
__global__ __launch_bounds__(256) void cvt_bf16(
    const float* __restrict__ src, unsigned short* __restrict__ dst, int n4)
{
    int i = blockIdx.x * blockDim.x + threadIdx.x;
    if (i < n4) {
        float4 v = ((const float4*)src)[i];
        uint2 h;
        h.x = pkbf16(v.x, v.y); h.y = pkbf16(v.z, v.w);
        ((uint2*)dst)[i] = h;
    }
}

__global__ __launch_bounds__(256) void cvt_bf16_w4(
    const float* __restrict__ w0, const float* __restrict__ w1,
    const float* __restrict__ w2, const float* __restrict__ w3,
    unsigned short* __restrict__ d0, unsigned short* __restrict__ d1,
    unsigned short* __restrict__ d2, unsigned short* __restrict__ d3)
{
    const int z = blockIdx.y;
    const float* src = (z == 0) ? w0 : (z == 1) ? w1 : (z == 2) ? w2 : w3;
    unsigned short* dst = (z == 0) ? d0 : (z == 1) ? d1 : (z == 2) ? d2 : d3;
    int i = blockIdx.x * blockDim.x + threadIdx.x;
    float4 v = ((const float4*)src)[i];
    uint2 h;
    h.x = pkbf16(v.x, v.y); h.y = pkbf16(v.z, v.w);
    ((uint2*)dst)[i] = h;
}

// ---------------------------------------------------------------------------
// m97-structure bf16 GEMM (QKV variant)
// ---------------------------------------------------------------------------
__global__ __launch_bounds__(256, 2) void gemm_qkv(
    const unsigned short* __restrict__ xb,
    const unsigned short* __restrict__ Wqb, const float* __restrict__ bq,
    const unsigned short* __restrict__ Wkb, const float* __restrict__ bk,
    const unsigned short* __restrict__ Wvb, const float* __restrict__ bv,
    unsigned short* __restrict__ Qb, unsigned short* __restrict__ Kb,
    unsigned short* __restrict__ Vb)
{
    const int z = blockIdx.z;
    const unsigned short* B = (z == 0) ? Wqb : (z == 1) ? Wkb : Wvb;
    const float* bias        = (z == 0) ? bq  : (z == 1) ? bk  : bv;
    unsigned short* C        = (z == 0) ? Qb  : (z == 1) ? Kb  : Vb;
    const float oscale = (z == 0) ? 0.12751743f : 1.0f;  // log2(e)/sqrt(128)

    __shared__ alignas(16) unsigned short As[128 * 32];
    __shared__ alignas(16) unsigned short Bs[128 * 32];

    const int tid = threadIdx.x;
    const int m0 = blockIdx.y * 128, n0 = blockIdx.x * 128;
    const int w = tid >> 6, lane = tid & 63, lo = lane & 15, qd = lane >> 4;
    const int wm = (w >> 1) * 64, wn = (w & 1) * 64;
    const int rsel = lane >> 2, csel = (lane & 3) * 8;

    f32x4 acc[4][4] = {};

    for (int k0 = 0; k0 < DMODEL; k0 += 32) {
#pragma unroll
        for (int i = 0; i < 2; i++) {
            int c = w * 2 + i;
            ldg2lds16(&xb[(size_t)(m0 + c * 16 + rsel) * DMODEL + k0 + csel],
                      &As[c * 512]);
            ldg2lds16(&B [(size_t)(n0 + c * 16 + rsel) * DMODEL + k0 + csel],
                      &Bs[c * 512]);
        }
        __syncthreads();

        bf16x8 af[4], bfr[4];
#pragma unroll
        for (int i = 0; i < 4; i++)
            af[i] = *(const bf16x8*)&As[(wm + i * 16 + lo) * 32 + qd * 8];
#pragma unroll
        for (int j = 0; j < 4; j++)
            bfr[j] = *(const bf16x8*)&Bs[(wn + j * 16 + lo) * 32 + qd * 8];
#pragma unroll
        for (int i = 0; i < 4; i++)
#pragma unroll
            for (int j = 0; j < 4; j++)
                acc[i][j] = mfma16(af[i], bfr[j], acc[i][j]);
        __syncthreads();
    }

#pragma unroll
    for (int j = 0; j < 4; j++) {
        int n = n0 + wn + j * 16 + lo;
        float bv_ = bias[n];
#pragma unroll
        for (int i = 0; i < 4; i++) {
#pragma unroll
            for (int r = 0; r < 4; r++) {
                int m = m0 + wm + i * 16 + qd * 4 + r;
                C[(size_t)m * DMODEL + n] = f2b((acc[i][j][r] + bv_) * oscale);
            }
        }
    }
}

// Output projection variant: fp32 out + bias.
__global__ __launch_bounds__(256, 2) void gemm_out(
    const unsigned short* __restrict__ Aatt, const unsigned short* __restrict__ Wob,
    const float* __restrict__ bo, float* __restrict__ out)
{
    __shared__ alignas(16) unsigned short As[128 * 32];
    __shared__ alignas(16) unsigned short Bs[128 * 32];

    const int tid = threadIdx.x;
    const int m0 = blockIdx.y * 128, n0 = blockIdx.x * 128;
    const int w = tid >> 6, lane = tid & 63, lo = lane & 15, qd = lane >> 4;
    const int wm = (w >> 1) * 64, wn = (w & 1) * 64;
    const int rsel = lane >> 2, csel = (lane & 3) * 8;

    f32x4 acc[4][4] = {};

    for (int k0 = 0; k0 < DMODEL; k0 += 32) {
#pragma unroll
        for (int i = 0; i < 2; i++) {
            int c = w * 2 + i;
            ldg2lds16(&Aatt[(size_t)(m0 + c * 16 + rsel) * DMODEL + k0 + csel],
                      &As[c * 512]);
            ldg2lds16(&Wob [(size_t)(n0 + c * 16 + rsel) * DMODEL + k0 + csel],
                      &Bs[c * 512]);
        }
        __syncthreads();

        bf16x8 af[4], bfr[4];
#pragma unroll
        for (int i = 0; i < 4; i++)
            af[i] = *(const bf16x8*)&As[(wm + i * 16 + lo) * 32 + qd * 8];
#pragma unroll
        for (int j = 0; j < 4; j++)
            bfr[j] = *(const bf16x8*)&Bs[(wn + j * 16 + lo) * 32 + qd * 8];
#pragma unroll
        for (int i = 0; i < 4; i++)
#pragma unroll
            for (int j = 0; j < 4; j++)
                acc[i][j] = mfma16(af[i], bfr[j], acc[i][j]);
        __syncthreads();
    }

#pragma unroll
    for (int j = 0; j < 4; j++) {
        int n = n0 + wn + j * 16 + lo;
        float bv_ = bo[n];
#pragma unroll
        for (int i = 0; i < 4; i++) {
#pragma unroll
            for (int r = 0; r < 4; r++) {
                int m = m0 + wm + i * 16 + qd * 4 + r;
                out[(size_t)m * DMODEL + n] = acc[i][j][r] + bv_;
            }
        }
    }
}

// ---------------------------------------------------------------------------
// V transpose: Vb [s][n] -> Vt [n][s]
// ---------------------------------------------------------------------------
__global__ __launch_bounds__(256) void transpose_v(
    const unsigned short* __restrict__ Vb, unsigned short* __restrict__ Vt)
{
    __shared__ unsigned short tile[64 * 67];
    const int s0 = blockIdx.x * 64;
    const int d0 = blockIdx.y * 64;
    const int tid = threadIdx.x;
#pragma unroll
    for (int i = 0; i < 2; i++) {
        int chunk = tid + i * 256;
        int r = chunk >> 3, c8 = (chunk & 7) * 8;
        uint4 v = *(const uint4*)&Vb[(size_t)(s0 + r) * DMODEL + d0 + c8];
        const unsigned short* p = (const unsigned short*)&v;
#pragma unroll
        for (int j = 0; j < 8; j++) tile[r * 67 + c8 + j] = p[j];
    }
    __syncthreads();
#pragma unroll
    for (int i = 0; i < 2; i++) {
        int chunk = tid + i * 256;
        int r = chunk >> 3, c8 = (chunk & 7) * 8;
        unsigned short tmp[8];
#pragma unroll
        for (int j = 0; j < 8; j++) tmp[j] = tile[(c8 + j) * 67 + r];
        *(uint4*)&Vt[(size_t)(d0 + r) * S_LEN + s0 + c8] = *(uint4*)tmp;
    }
}

// ---------------------------------------------------------------------------
// Flash attention v7: occupancy restructure.
//   v6 post-mortem: dbuf prefetch was NEUTRAL -> the stall was never stage
//   latency (K/V are L2-hits). Real limiter: 2 blocks/CU, 2 waves/SIMD,
//   barrier-locked into the same phase. MFMA blocks its own wave, so a CU
//   with phase-locked waves serializes softmax(VALU) and MFMA phases
//   (27% Mfma + 48% VALU, ~25% dead).
//   v7: q-block 64 (4 waves x 16 q), single-buffered LDS = 40 KB
//   -> 4 independent blocks/CU (16 waves/CU, 4 waves/SIMD from desynced
//   blocks) so one block's VALU phase overlaps another's MFMA phase.
//   K/V staging per CU doubles but is L2-resident (13 TB/s << 34.5 TB/s).
//   exp2f -> __builtin_amdgcn_exp2f (guaranteed raw v_exp_f32).
// ---------------------------------------------------------------------------
__global__ __launch_bounds__(256, 4) void attn_kernel(
    const unsigned short* __restrict__ Qb, const unsigned short* __restrict__ Kb,
    const unsigned short* __restrict__ Vt, unsigned short* __restrict__ Ob)
{
    const int id = blockIdx.x;
    const int xcd = id & 7, slot = id >> 3;          // slot 0..127
    const int h  = (xcd << 1) | (slot >> 6);         // 2 heads per XCD
    const int q0 = (slot & 63) * 64;                 // 64-query block

    __shared__ alignas(16) unsigned short Ks[64 * 128];    // [key][d] swizzled (16 KB)
    __shared__ alignas(16) unsigned short Vts[128 * 64];   // [d][key] swizzled (16 KB)
    __shared__ alignas(16) unsigned short Ps[4][16 * 64];  // per-wave [q][key] swizzled (8 KB)

    const int tid = threadIdx.x;
    const int w = tid >> 6, lane = tid & 63, lo = lane & 15, qd = lane >> 4;

    // Q fragments direct from global: wave w owns q rows w*16 .. w*16+15
    bf16x8 qf[4];
    {
        const unsigned short* qrow =
            &Qb[(size_t)(q0 + w * 16 + lo) * DMODEL + h * HDIM];
#pragma unroll
        for (int kk = 0; kk < 4; kk++)
            qf[kk] = *(const bf16x8*)&qrow[kk * 32 + qd * 8];
    }

    f32x4 o_acc[8] = {};
    float l_run = 0.f;   // lane's q = lo

    for (int kb = 0; kb < S_LEN / 64; kb++) {
        const int key0 = kb * 64;

        // K staging: wave w -> key rows w*16..w*16+15
#pragma unroll
        for (int i = 0; i < 4; i++) {
            int r = w * 16 + i * 4 + (lane >> 4);
            int c = (lane & 15) ^ (r & 7);
            ldg2lds16(&Kb[(size_t)(key0 + r) * DMODEL + h * HDIM + c * 8],
                      &Ks[(w * 16 + i * 4) * 128]);
        }
        // V staging: wave w -> d rows w*32..w*32+31
#pragma unroll
        for (int i = 0; i < 4; i++) {
            int r = w * 32 + i * 8 + (lane >> 3);
            int c = (lane & 7) ^ (r & 7);
            ldg2lds16(&Vt[(size_t)(h * HDIM + r) * S_LEN + key0 + c * 8],
                      &Vts[(w * 32 + i * 8) * 64]);
        }
        __syncthreads();

        // S^T[key 64][q 16] = K Q^T : A = K-frag (m=key), B = Q-frag (n=q)
        f32x4 s[4] = {};
        __builtin_amdgcn_s_setprio(1);
#pragma unroll
        for (int kk = 0; kk < 4; kk++) {
#pragma unroll
            for (int t = 0; t < 4; t++) {
                bf16x8 kf = *(const bf16x8*)
                    &Ks[(t * 16 + lo) * 128 + (((kk * 4 + qd) ^ (lo & 7)) * 8)];
                s[t] = mfma16(kf, qf[kk], s[t]);
            }
        }
        __builtin_amdgcn_s_setprio(0);

        // exp2 + packed P write + per-lane l accumulate.
        // Lane's C-tile: q = lo, keys = t*16 + qd*4 + r (r consecutive!)
        {
            const int row = lo;
            float lsum = 0.f;
#pragma unroll
            for (int t = 0; t < 4; t++) {
                float p0 = __builtin_amdgcn_exp2f(s[t][0]);
                float p1 = __builtin_amdgcn_exp2f(s[t][1]);
                float p2 = __builtin_amdgcn_exp2f(s[t][2]);
                float p3 = __builtin_amdgcn_exp2f(s[t][3]);
                lsum += (p0 + p1) + (p2 + p3);
                uint2 pkv;
                pkv.x = pkbf16(p0, p1);
                pkv.y = pkbf16(p2, p3);
                // 16B chunk c16 = t*2+(qd>>1), swizzled by (row&7); 8B half = qd&1
                int swz = (t * 2 + (qd >> 1)) ^ (lo & 7);
                *(uint2*)&Ps[w][row * 64 + swz * 8 + (qd & 1) * 4] = pkv;
            }
            l_run += lsum;
        }
        asm volatile("s_waitcnt lgkmcnt(0)" ::: "memory");  // wave-local P w->r

        // O += P V
        __builtin_amdgcn_s_setprio(1);
#pragma unroll
        for (int kk = 0; kk < 2; kk++) {
            bf16x8 pf = *(const bf16x8*)
                &Ps[w][lo * 64 + (((kk * 4 + qd) ^ (lo & 7)) * 8)];
#pragma unroll
            for (int dt = 0; dt < 8; dt++) {
                bf16x8 vf = *(const bf16x8*)
                    &Vts[(dt * 16 + lo) * 64 + (((kk * 4 + qd) ^ (lo & 7)) * 8)];
                o_acc[dt] = mfma16(pf, vf, o_acc[dt]);
            }
        }
        __builtin_amdgcn_s_setprio(0);

        __syncthreads();
    }

    // epilogue: l lives at lane (q & 15) after qd-reduction; redistribute to
    // the O C-layout rows (q = qd*4 + r) via shuffle.
    {
        float l = l_run;
        l += __shfl_xor(l, 16);
        l += __shfl_xor(l, 32);          // now uniform across qd for q=lo
        float inv_l[4];
#pragma unroll
        for (int r = 0; r < 4; r++)
            inv_l[r] = 1.0f / __shfl(l, qd * 4 + r);
#pragma unroll
        for (int dt = 0; dt < 8; dt++) {
#pragma unroll
            for (int r = 0; r < 4; r++) {
                int row = q0 + w * 16 + qd * 4 + r;
                int col = h * HDIM + dt * 16 + lo;
                Ob[(size_t)row * DMODEL + col] = f2b(o_acc[dt][r] * inv_l[r]);
            }
        }
    }
}

// ---------------------------------------------------------------------------
extern "C" void kernel_launch(void* const* d_in, const int* in_sizes, int n_in,
                              void* d_out, int out_size, void* d_ws, size_t ws_size,
                              hipStream_t stream)
{
    const float* x  = (const float*)d_in[0];
    const float* Wq = (const float*)d_in[1];
    const float* bq = (const float*)d_in[2];
    const float* Wk = (const float*)d_in[3];
    const float* bk = (const float*)d_in[4];
    const float* Wv = (const float*)d_in[5];
    const float* bv = (const float*)d_in[6];
    const float* Wo = (const float*)d_in[7];
    const float* bo = (const float*)d_in[8];
    float* out = (float*)d_out;

    const size_t N = (size_t)S_LEN * DMODEL;   // 8M elems
    const size_t W = (size_t)DMODEL * DMODEL;  // 4M elems
    unsigned short* Qb  = (unsigned short*)d_ws;
    unsigned short* Kb  = Qb + N;
    unsigned short* Vb  = Kb + N;
    unsigned short* xbv = Vb + N;
    unsigned short* Wqb = xbv + N;
    unsigned short* Wkb = Wqb + W;
    unsigned short* Wvb = Wkb + W;
    unsigned short* Wob = Wvb + W;
    unsigned short* Vt  = xbv;   // alias after gemm_qkv
    unsigned short* Ob  = Vb;    // alias after transpose

    cvt_bf16<<<(int)(N / 4 / 256), 256, 0, stream>>>(x, xbv, (int)(N / 4));
    cvt_bf16_w4<<<dim3((unsigned)(W / 4 / 256), 4), 256, 0, stream>>>(
        Wq, Wk, Wv, Wo, Wqb, Wkb, Wvb, Wob);

    gemm_qkv<<<dim3(DMODEL / 128, S_LEN / 128, 3), 256, 0, stream>>>(
        xbv, Wqb, bq, Wkb, bk, Wvb, bv, Qb, Kb, Vb);

    transpose_v<<<dim3(S_LEN / 64, DMODEL / 64), 256, 0, stream>>>(Vb, Vt);

    attn_kernel<<<1024, 256, 0, stream>>>(Qb, Kb, Vt, Ob);

    gemm_out<<<dim3(DMODEL / 128, S_LEN / 128), 256, 0, stream>>>(Ob, Wob, bo, out);
}